// Round 12
// baseline (248.326 us; speedup 1.0000x reference)
//
#include <hip/hip_runtime.h>

// NCC loss: 1 - mean( cross^2 / (pvar*tvar + 1e-8) ) over 9^3 zero-padded
// box windows, input (4,1,160,160,160) fp32.
//
// R17: R16 (122.8us, best) + ZCHUNK 40->80. Accounting: at ZCHUNK=40 each
// (x,y,batch) column fetches 188 slices per 160 outputs (1.175x z-overfetch,
// 4 warmup boundaries); at 80 it's 168/160 = 1.05x -> FETCH ~331->296 MB,
// warmup work per output halves, and grid = 800 blocks ~= one clean round at
// 3 blocks/CU (768 slots) -> less dispatch tail. Loop: 8 x 9-step rolled
// body (I-cache safe) + 8-step static epilogue; ring slots stay compile-time
// static ((s+8)%9). NOTHING else changes vs R16 (3 cols/thread, 64 VGPR,
// 3 stg + 1 red wave, depth-1 prefetch, one barrier/step, dbuf s2).
// Known secondary issue kept as-is: 3-dword stg writes can't merge to b128
// -> ~90 conflict-cycles/step (~7%); structural (40 writers > 32 banks).

#define DSZ    160
#define NBATCH 4
#define RAD    4
#define TX     16
#define TY     16
#define ZCHUNK 80
#define SLICE  (DSZ*DSZ)
#define VOL    (DSZ*DSZ*DSZ)
#define WINV   (1.0f/729.0f)
#define NVOX_INV (1.0f/16384000.0f)

#define NROW 24        // halo rows per tile
#define BLK  256       // 3 staging waves (tid<192, all active) + 1 reduction wave

#define S2_RS 20                 // row stride: 16 outputs + pad
#define S2_FS (NROW*S2_RS)       // 480 floats per field
#define S2_BUF (5*S2_FS)         // 2400 floats per parity buffer

__device__ __forceinline__ float dpp_shl1(float x) {  // lane i <- lane i+1 (16-lane row, OOB=0)
    return __int_as_float(__builtin_amdgcn_update_dpp(0, __float_as_int(x), 0x101, 0xf, 0xf, true));
}
__device__ __forceinline__ float dpp_shl2(float x) {  // lane i <- lane i+2
    return __int_as_float(__builtin_amdgcn_update_dpp(0, __float_as_int(x), 0x102, 0xf, 0xf, true));
}
__device__ __forceinline__ float dpp_shl3(float x) {  // lane i <- lane i+3
    return __int_as_float(__builtin_amdgcn_update_dpp(0, __float_as_int(x), 0x103, 0xf, 0xf, true));
}

__global__ __launch_bounds__(BLK, 4)
void ncc_main(const float* __restrict__ pred, const float* __restrict__ tgt,
              float* __restrict__ accum)
{
    const int tid = threadIdx.x;
    const int row = tid >> 3;      // 0..23 halo row (staging threads)
    const int g   = tid & 7;       // 0..7 col-triple group; ALL active
    const int ox  = blockIdx.x * TX;
    const int oy  = blockIdx.y * TY;
    const int batch = blockIdx.z >> 1;
    const int z0  = (blockIdx.z & 1) * ZCHUNK;

    __shared__ float s2[2*S2_BUF];   // 19.2 KB, double-buffered [f][y][x pad20]

    const bool stg = (tid < 192);
    const bool red = (tid >= 192);               // dedicated reduction wave
    const int  gy  = oy - RAD + row;
    const int  gx0 = ox - RAD + g*3;             // 3 halo cols per thread
    const bool ldok = stg && (gy >= 0) && (gy < DSZ) && (gx0 >= 0) && (gx0 + 2 < DSZ);
    const int  base = batch*VOL + gy*DSZ + gx0;  // only used under ldok

    // register ring of raw slice values (own 3 columns), chunk-local slots
    float rp[9][3], rt[9][3];
    float zs[5][3];
    #pragma unroll
    for (int k = 0; k < 9; ++k)
        #pragma unroll
        for (int j = 0; j < 3; ++j) { rp[k][j] = 0.f; rt[k][j] = 0.f; }
    #pragma unroll
    for (int f = 0; f < 5; ++f)
        #pragma unroll
        for (int j = 0; j < 3; ++j) zs[f][j] = 0.f;

    // ---- warm-up: chunk-local slices 0..7 (z = z0-4 .. z0+3) -> slots 0..7
    if (stg) {
        #pragma unroll
        for (int i = 0; i < 8; ++i) {
            int z = z0 - RAD + i;
            if (z >= 0) {                       // uniform; z < DSZ always here
                float3 p3 = {0,0,0}, t3 = {0,0,0};
                if (ldok) {
                    p3 = *(const float3*)(pred + base + z*SLICE);
                    t3 = *(const float3*)(tgt  + base + z*SLICE);
                }
                const float pc[3] = {p3.x, p3.y, p3.z};
                const float tc[3] = {t3.x, t3.y, t3.z};
                #pragma unroll
                for (int j = 0; j < 3; ++j) {
                    zs[0][j] += pc[j];        zs[1][j] += tc[j];
                    zs[2][j] += pc[j]*pc[j];  zs[3][j] += tc[j]*tc[j];
                    zs[4][j] += pc[j]*tc[j];
                    rp[i][j] = pc[j];  rt[i][j] = tc[j];
                }
            }
        }
    }

    // ---- streaming prefetch of the next add-slice (depth 1) ----
    int za = z0 + RAD;                      // absolute z of next fetch
    int zmax = z0 + ZCHUNK + RAD;           // last useful slice + 1
    if (zmax > DSZ) zmax = DSZ;
    float3 pa3 = {0,0,0}, ta3 = {0,0,0};

#define PF_NEXT() do {                                                        \
    float3 _p = {0,0,0}, _t = {0,0,0};                                        \
    if (ldok && za < zmax) {                                                  \
        _p = *(const float3*)(pred + base + za*SLICE);                        \
        _t = *(const float3*)(tgt  + base + za*SLICE);                        \
    }                                                                         \
    pa3 = _p; ta3 = _t; ++za;                                                 \
} while (0)

    if (stg) PF_NEXT();  // slice for step 0

    int pb = 1;          // parity buffer toggle (first step -> 0)
    float acc = 0.f;

#define NCC_STEP(SLOT) do {                                                   \
    pb ^= 1;                                                                  \
    float* s2w = s2 + pb*S2_BUF;                                              \
    if (stg) {                                                                \
        const float pc[3] = {pa3.x, pa3.y, pa3.z};                            \
        const float tc[3] = {ta3.x, ta3.y, ta3.z};                            \
        PF_NEXT();  /* issue slice s+1; full step to complete */              \
        _Pragma("unroll")                                                     \
        for (int j = 0; j < 3; ++j) {                                         \
            float ps = rp[SLOT][j], qs = rt[SLOT][j];                         \
            float d0 = pc[j] - ps, d1 = tc[j] - qs;                           \
            zs[0][j] += d0;                                                   \
            zs[1][j] += d1;                                                   \
            zs[2][j] += d0*(pc[j] + ps);                                      \
            zs[3][j] += d1*(tc[j] + qs);                                      \
            zs[4][j] += pc[j]*tc[j] - ps*qs;                                  \
            rp[SLOT][j] = pc[j];  rt[SLOT][j] = tc[j];                        \
        }                                                                     \
        _Pragma("unroll")                                                     \
        for (int f = 0; f < 5; ++f) {                                         \
            float v0  = zs[f][0];                                             \
            float v01 = v0 + zs[f][1];                                        \
            float G   = v01 + zs[f][2];        /* 3-col group sum */          \
            float G1 = dpp_shl1(G);                                           \
            float G2 = dpp_shl2(G);                                           \
            float A0 = dpp_shl3(v0);           /* v0(m+3)  */                 \
            float A1 = dpp_shl3(v01);          /* v01(m+3) */                 \
            float S  = G + G1 + G2;            /* halo cols 3m..3m+8 */       \
            float* dst = &s2w[f*S2_FS + row*S2_RS + 3*g];                     \
            if (g < 5) {                                                      \
                dst[0] = S;                    /* out 3m   */                 \
                dst[1] = S - v0  + A0;         /* out 3m+1 */                 \
                dst[2] = S - v01 + A1;         /* out 3m+2 */                 \
            } else if (g == 5) {                                              \
                dst[0] = S;                    /* out 15   */                 \
            }                                                                 \
        }                                                                     \
    }                                                                         \
    __syncthreads();                                                          \
    if (red) {                                                                \
        const int x = tid & 15, yq = ((tid >> 4) & 3)*4;                      \
        float S[5][4];                                                        \
        _Pragma("unroll")                                                     \
        for (int f = 0; f < 5; ++f) {                                         \
            const float* col = &s2w[f*S2_FS + x];                             \
            float r0 = col[(yq+0)*S2_RS], r1 = col[(yq+1)*S2_RS];             \
            float r2 = col[(yq+2)*S2_RS], r3 = col[(yq+3)*S2_RS];             \
            float run = r0+r1+r2+r3 + col[(yq+4)*S2_RS] + col[(yq+5)*S2_RS]   \
                      + col[(yq+6)*S2_RS] + col[(yq+7)*S2_RS];                \
            run += col[(yq+8)*S2_RS];        S[f][0] = run;                   \
            run += col[(yq+9)*S2_RS]  - r0;  S[f][1] = run;                   \
            run += col[(yq+10)*S2_RS] - r1;  S[f][2] = run;                   \
            run += col[(yq+11)*S2_RS] - r2;  S[f][3] = run;                   \
        }                                                                     \
        _Pragma("unroll")                                                     \
        for (int i = 0; i < 4; ++i) {                                         \
            float Sp = S[0][i], St = S[1][i];                                 \
            float cross = S[4][i] - Sp*St*WINV;                               \
            float pv    = S[2][i] - Sp*Sp*WINV;                               \
            float tv    = S[3][i] - St*St*WINV;                               \
            acc += cross*cross / (pv*tv + 1e-8f);                             \
        }                                                                     \
    }                                                                         \
} while (0)

    // 80 steps; slot = (s+8)%9 -> period-9 pattern [8,0,1,2,3,4,5,6,7]
    // 72 steps rolled (8 iters), 8-step static epilogue.
    for (int it = 0; it < 8; ++it) {
        NCC_STEP(8); NCC_STEP(0); NCC_STEP(1);
        NCC_STEP(2); NCC_STEP(3); NCC_STEP(4);
        NCC_STEP(5); NCC_STEP(6); NCC_STEP(7);
    }
    NCC_STEP(8); NCC_STEP(0); NCC_STEP(1); NCC_STEP(2);
    NCC_STEP(3); NCC_STEP(4); NCC_STEP(5); NCC_STEP(6);
#undef NCC_STEP
#undef PF_NEXT

    // all cc partials live in the reduction wave (tid 192..255)
    if (red) {
        float v = acc;
        #pragma unroll
        for (int off = 32; off > 0; off >>= 1) v += __shfl_down(v, off, 64);
        if (tid == 192) atomicAdd(accum, v);
    }
}

__global__ void ncc_final(const float* __restrict__ accum, float* __restrict__ out)
{
    out[0] = 1.0f - accum[0] * NVOX_INV;
}

extern "C" void kernel_launch(void* const* d_in, const int* in_sizes, int n_in,
                              void* d_out, int out_size, void* d_ws, size_t ws_size,
                              hipStream_t stream)
{
    const float* pred = (const float*)d_in[0];
    const float* tgt  = (const float*)d_in[1];
    float* out = (float*)d_out;
    float* ws  = (float*)d_ws;

    hipMemsetAsync(ws, 0, sizeof(float), stream);
    dim3 grid(DSZ/TX, DSZ/TY, NBATCH*2);   // 10 x 10 x 8 = 800 blocks
    ncc_main<<<grid, BLK, 0, stream>>>(pred, tgt, ws);
    ncc_final<<<1, 1, 0, stream>>>(ws, out);
}